// Round 5
// baseline (1220.631 us; speedup 1.0000x reference)
//
#include <hip/hip_runtime.h>

#define N_READ   200000
#define N_INTRON 50000
#define N_EDGES  2000000

#define NB    256                          // edge-segment blocks for hist/scatter
#define EPB   ((N_EDGES + NB - 1) / NB)    // 7813 edges per block
#define NBUK  782                          // buckets (782*64>=50000, 782*256>=200000)
#define NITEMS (NBUK * NB)                 // 200192 (divisible by 256)

typedef float f4 __attribute__((ext_vector_type(4)));
typedef float f2 __attribute__((ext_vector_type(2)));

// ---------------- bucket histogram of int keys (per-block LDS, no global atomics) ----------------
__global__ void kb_hist_i32(const int* __restrict__ keys, int shift, int* __restrict__ hist) {
  __shared__ int h[1024];
  const int t = threadIdx.x, b = blockIdx.x;
  for (int k = t; k < 1024; k += 256) h[k] = 0;
  __syncthreads();
  const int s0 = b * EPB;
  const int s1 = (s0 + EPB < N_EDGES) ? s0 + EPB : N_EDGES;
  for (int i = s0 + t; i < s1; i += 256) atomicAdd(&h[keys[i] >> shift], 1);
  __syncthreads();
  for (int k = t; k < NBUK; k += 256) hist[k * NB + b] = h[k];
}

__global__ void kb_hist_u16(const unsigned short* __restrict__ keys, int shift,
                            int* __restrict__ hist) {
  __shared__ int h[1024];
  const int t = threadIdx.x, b = blockIdx.x;
  for (int k = t; k < 1024; k += 256) h[k] = 0;
  __syncthreads();
  const int s0 = b * EPB;
  const int s1 = (s0 + EPB < N_EDGES) ? s0 + EPB : N_EDGES;
  for (int i = s0 + t; i < s1; i += 256) atomicAdd(&h[(int)keys[i] >> shift], 1);
  __syncthreads();
  for (int k = t; k < NBUK; k += 256) hist[k * NB + b] = h[k];
}

// ---------------- exclusive scan (3 phases) ----------------
__global__ void k_scan1(const int* __restrict__ cnt, int* __restrict__ rp,
                        int* __restrict__ bsum, int n) {
  __shared__ int lds[256];
  int t = threadIdx.x;
  int i = blockIdx.x * 256 + t;
  int v = (i < n) ? cnt[i] : 0;
  lds[t] = v;
  __syncthreads();
  for (int off = 1; off < 256; off <<= 1) {
    int x = (t >= off) ? lds[t - off] : 0;
    __syncthreads();
    lds[t] += x;
    __syncthreads();
  }
  if (i < n) rp[i + 1] = lds[t];
  if (t == 255) bsum[blockIdx.x] = lds[255];
}

__global__ void k_scan2(int* __restrict__ bsum, int nb) {
  __shared__ int lds[1024];
  int t = threadIdx.x;
  int v = (t < nb) ? bsum[t] : 0;
  lds[t] = v;
  __syncthreads();
  for (int off = 1; off < 1024; off <<= 1) {
    int x = (t >= off) ? lds[t - off] : 0;
    __syncthreads();
    lds[t] += x;
    __syncthreads();
  }
  if (t < nb) bsum[t] = lds[t];
}

__global__ void k_scan3b(int* __restrict__ rp, const int* __restrict__ bsum, int n) {
  int i = blockIdx.x * 256 + threadIdx.x;
  if (i >= n) return;
  int off = (blockIdx.x == 0) ? 0 : bsum[blockIdx.x - 1];
  rp[i + 1] += off;
  if (i == 0) rp[0] = 0;
}

// ---------------- P1: scatter original edges into intron buckets ----------------
__global__ void kb_scat1(const int* __restrict__ src, const int* __restrict__ dst,
                         const int* __restrict__ scanA,
                         int* __restrict__ A_read, unsigned short* __restrict__ A_intr) {
  __shared__ int cur[1024];
  const int t = threadIdx.x, b = blockIdx.x;
  for (int k = t; k < NBUK; k += 256) cur[k] = scanA[k * NB + b];
  __syncthreads();
  const int s0 = b * EPB;
  const int s1 = (s0 + EPB < N_EDGES) ? s0 + EPB : N_EDGES;
  for (int i = s0 + t; i < s1; i += 256) {
    int s = src[i], d = dst[i];
    int slot = atomicAdd(&cur[d >> 6], 1);
    A_read[slot] = s;
    A_intr[slot] = (unsigned short)d;
  }
}

// ---------------- P2: scatter intron-ordered stream into read buckets ----------------
__global__ void kb_scat2(const int* __restrict__ A_read, const unsigned short* __restrict__ A_intr,
                         const int* __restrict__ scanB, unsigned* __restrict__ B2,
                         int* __restrict__ C_read, unsigned short* __restrict__ C_intr) {
  __shared__ int cur[1024];
  const int t = threadIdx.x, b = blockIdx.x;
  for (int k = t; k < NBUK; k += 256) cur[k] = scanB[k * NB + b];
  __syncthreads();
  const int s0 = b * EPB;
  const int s1 = (s0 + EPB < N_EDGES) ? s0 + EPB : N_EDGES;
  for (int i = s0 + t; i < s1; i += 256) {
    int r = A_read[i];
    unsigned short ti = A_intr[i];
    int slot = atomicAdd(&cur[r >> 8], 1);
    B2[slot] = ((unsigned)ti << 8) | (unsigned)(r & 255);  // 16+8 = 24 bits
    C_read[slot] = r;
    C_intr[slot] = ti;
  }
}

// ---------------- P3: scatter read-ordered stream into intron buckets ----------------
__global__ void kb_scat3(const int* __restrict__ C_read, const unsigned short* __restrict__ C_intr,
                         const int* __restrict__ scanC, unsigned* __restrict__ D) {
  __shared__ int cur[1024];
  const int t = threadIdx.x, b = blockIdx.x;
  for (int k = t; k < NBUK; k += 256) cur[k] = scanC[k * NB + b];
  __syncthreads();
  const int s0 = b * EPB;
  const int s1 = (s0 + EPB < N_EDGES) ? s0 + EPB : N_EDGES;
  for (int i = s0 + t; i < s1; i += 256) {
    int r = C_read[i];
    unsigned short ti = C_intr[i];
    int slot = atomicAdd(&cur[(int)ti >> 6], 1);
    D[slot] = ((unsigned)r << 6) | (unsigned)(ti & 63);  // 18+6 = 24 bits
  }
}

// ---------------- fine CSR per bucket: local hist + LDS scan + scatter ----------------
template <int NBINS, int SH, typename PT>
__global__ void kb_fine(const unsigned* __restrict__ bk, const int* __restrict__ scan,
                        int* __restrict__ rp, float* __restrict__ rs,
                        PT* __restrict__ csr, int n_nodes) {
  __shared__ int hist[NBINS], cur[NBINS], lds[256];
  const int t = threadIdx.x, k = blockIdx.x;
  for (int j = t; j < NBINS; j += 256) hist[j] = 0;
  __syncthreads();
  const int s0 = scan[k * NB];
  const int e0 = (k + 1 < NBUK) ? scan[(k + 1) * NB] : N_EDGES;
  for (int i = s0 + t; i < e0; i += 256) atomicAdd(&hist[bk[i] & (NBINS - 1)], 1);
  __syncthreads();
  int v = (t < NBINS) ? hist[t] : 0;
  lds[t] = v;
  __syncthreads();
  for (int off = 1; off < 256; off <<= 1) {
    int x = (t >= off) ? lds[t - off] : 0;
    __syncthreads();
    lds[t] += x;
    __syncthreads();
  }
  if (t < NBINS) {
    int base = s0 + lds[t] - hist[t];
    cur[t] = base;
    int n = k * NBINS + t;
    if (n < n_nodes) {
      rp[n] = base;
      rs[n] = rsqrtf((float)(hist[t] > 0 ? hist[t] : 1));
    }
  }
  if (k == NBUK - 1 && t == 0) rp[n_nodes] = N_EDGES;
  __syncthreads();
  for (int i = s0 + t; i < e0; i += 256) {
    unsigned v2 = bk[i];
    int slot = atomicAdd(&cur[v2 & (NBINS - 1)], 1);
    csr[slot] = (PT)(v2 >> SH);
  }
}

// ---------------- layer-0 input prep: pad 10->16 and pre-scale by rs_read ----------------
__global__ void k_prep_h0(const float* __restrict__ h_read, const float* __restrict__ rs_r,
                          float* __restrict__ h16) {
  int i = blockIdx.x * blockDim.x + threadIdx.x;
  if (i >= N_READ * 16) return;
  int n = i >> 4, c = i & 15;
  h16[i] = (c < 10) ? h_read[n * 10 + c] * rs_r[n] : 0.0f;
}

__global__ void k_prep_W0(const float* __restrict__ W0, float* __restrict__ W0p) {
  int i = blockIdx.x * blockDim.x + threadIdx.x;
  if (i >= 16 * 64) return;
  int k = i >> 6, j = i & 63;
  W0p[i] = (k < 10) ? W0[k * 64 + j] : 0.0f;
}

// ---------------- fused aggregate + GEMM + epilogue layer (round-2/4 structure) ----------------
template <int DIN, int DOUT, bool FC, typename ET>
__launch_bounds__(256)
__global__ void k_layer(const float* __restrict__ hsrc, const int* __restrict__ rp,
                        const ET* __restrict__ eidx, const float* __restrict__ rs_dst,
                        const float* __restrict__ W, const float* __restrict__ bias,
                        const float* __restrict__ atts, int li,
                        const float* __restrict__ rs_next,  // may be null
                        float* __restrict__ hout,
                        const float* __restrict__ fcw, const float* __restrict__ fcb,
                        float* __restrict__ fcout, int n_dst) {
  constexpr int NT = 32;
  constexpr int RSTR = DIN + 4;  // padded LDS row stride (floats)
  __shared__ float rows[NT * RSTR];
  const int tid = threadIdx.x;
  const int nbase = blockIdx.x * NT;
  const int team = tid >> 6, lane = tid & 63;

  if constexpr (DIN == 128) {
    const int sub = lane >> 5, l32 = lane & 31;
    for (int tl = 0; tl < 4; ++tl) {
      const int t = team * 8 + tl * 2 + sub;
      const int n = nbase + t;
      f4 a0 = {0.f, 0.f, 0.f, 0.f}, a1 = a0, a2 = a0, a3 = a0;
      if (n < n_dst) {
        const int e0 = rp[n], e1 = rp[n + 1];
        int e = e0;
        for (; e + 4 <= e1; e += 4) {
          int s0 = (int)eidx[e], s1 = (int)eidx[e + 1];
          int s2 = (int)eidx[e + 2], s3 = (int)eidx[e + 3];
          a0 += *(const f4*)&hsrc[(size_t)s0 * 128 + l32 * 4];
          a1 += *(const f4*)&hsrc[(size_t)s1 * 128 + l32 * 4];
          a2 += *(const f4*)&hsrc[(size_t)s2 * 128 + l32 * 4];
          a3 += *(const f4*)&hsrc[(size_t)s3 * 128 + l32 * 4];
        }
        for (; e < e1; ++e) a0 += *(const f4*)&hsrc[(size_t)(int)eidx[e] * 128 + l32 * 4];
        a0 = (a0 + a1) + (a2 + a3);
        a0 *= rs_dst[n];
      }
      *(f4*)&rows[t * RSTR + l32 * 4] = a0;
    }
  } else if constexpr (DIN == 64) {
    const int sub = lane >> 4, l16 = lane & 15;
    for (int tl = 0; tl < 2; ++tl) {
      const int t = team * 8 + tl * 4 + sub;
      const int n = nbase + t;
      f4 a0 = {0.f, 0.f, 0.f, 0.f}, a1 = a0, a2 = a0, a3 = a0;
      if (n < n_dst) {
        const int e0 = rp[n], e1 = rp[n + 1];
        int e = e0;
        for (; e + 4 <= e1; e += 4) {
          int s0 = (int)eidx[e], s1 = (int)eidx[e + 1];
          int s2 = (int)eidx[e + 2], s3 = (int)eidx[e + 3];
          a0 += *(const f4*)&hsrc[(size_t)s0 * 64 + l16 * 4];
          a1 += *(const f4*)&hsrc[(size_t)s1 * 64 + l16 * 4];
          a2 += *(const f4*)&hsrc[(size_t)s2 * 64 + l16 * 4];
          a3 += *(const f4*)&hsrc[(size_t)s3 * 64 + l16 * 4];
        }
        for (; e < e1; ++e) a0 += *(const f4*)&hsrc[(size_t)(int)eidx[e] * 64 + l16 * 4];
        a0 = (a0 + a1) + (a2 + a3);
        a0 *= rs_dst[n];
      }
      *(f4*)&rows[t * RSTR + l16 * 4] = a0;
    }
  } else {  // DIN == 16
    const int sub = lane >> 3, l8 = lane & 7;
    const int t = team * 8 + sub;
    const int n = nbase + t;
    f2 a0 = {0.f, 0.f}, a1 = a0, a2 = a0, a3 = a0;
    if (n < n_dst) {
      const int e0 = rp[n], e1 = rp[n + 1];
      int e = e0;
      for (; e + 4 <= e1; e += 4) {
        int s0 = (int)eidx[e], s1 = (int)eidx[e + 1];
        int s2 = (int)eidx[e + 2], s3 = (int)eidx[e + 3];
        a0 += *(const f2*)&hsrc[(size_t)s0 * 16 + l8 * 2];
        a1 += *(const f2*)&hsrc[(size_t)s1 * 16 + l8 * 2];
        a2 += *(const f2*)&hsrc[(size_t)s2 * 16 + l8 * 2];
        a3 += *(const f2*)&hsrc[(size_t)s3 * 16 + l8 * 2];
      }
      for (; e < e1; ++e) a0 += *(const f2*)&hsrc[(size_t)(int)eidx[e] * 16 + l8 * 2];
      a0 = (a0 + a1) + (a2 + a3);
      a0 *= rs_dst[n];
    }
    *(f2*)&rows[t * RSTR + l8 * 2] = a0;
  }
  __syncthreads();

  // GEMM: thread computes NPT nodes x 4 cols; nodes interleaved by NG
  constexpr int JG = DOUT / 4;
  constexpr int NG = 256 / JG;
  constexpr int NPT = NT / NG;
  const int jg = tid % JG, ng = tid / JG;
  const int j0 = jg * 4;

  f4 acc[NPT];
#pragma unroll
  for (int p = 0; p < NPT; ++p) acc[p] = (f4){0.f, 0.f, 0.f, 0.f};

#pragma unroll 2
  for (int k = 0; k < DIN; k += 4) {
    f4 w[4];
#pragma unroll
    for (int u = 0; u < 4; ++u) w[u] = *(const f4*)&W[(k + u) * DOUT + j0];
#pragma unroll
    for (int p = 0; p < NPT; ++p) {
      f4 r = *(const f4*)&rows[(ng + p * NG) * RSTR + k];
#pragma unroll
      for (int u = 0; u < 4; ++u) acc[p] += r[u] * w[u];
    }
  }

  const float gate = 1.f / (1.f + __expf(-atts[li]));
  const f4 b4 = *(const f4*)&bias[j0];

  if constexpr (!FC) {
#pragma unroll
    for (int p = 0; p < NPT; ++p) {
      const int nl = ng + p * NG;
      const int n = nbase + nl;
      if (n < n_dst) {
        f4 v = (acc[p] + b4) * gate;
#pragma unroll
        for (int c = 0; c < 4; ++c) v[c] = fmaxf(v[c], 0.f);
        if (rs_next) v *= rs_next[n];
        *(f4*)&hout[(size_t)n * DOUT + j0] = v;
      }
    }
  } else {
    __syncthreads();  // everyone done reading rows before we overwrite it
#pragma unroll
    for (int p = 0; p < NPT; ++p) {
      const int nl = ng + p * NG;
      f4 v = (acc[p] + b4) * gate;
#pragma unroll
      for (int c = 0; c < 4; ++c) v[c] = fmaxf(v[c], 0.f);
      *(f4*)&rows[nl * RSTR + j0] = v;
    }
    __syncthreads();
    // fc: 256 threads = 32 nodes x 2 cols x 4 partial-sums
    const int nl = tid >> 3, c = (tid >> 2) & 1, part = tid & 3;
    float s = 0.f;
    const int k0 = part * 32;
#pragma unroll 8
    for (int k = k0; k < k0 + 32; ++k) s += rows[nl * RSTR + k] * fcw[k * 2 + c];
    s += __shfl_xor(s, 1);
    s += __shfl_xor(s, 2);
    const int n = nbase + nl;
    if (part == 0 && n < n_dst) fcout[n * 2 + c] = s + fcb[c];
  }
}

extern "C" void kernel_launch(void* const* d_in, const int* in_sizes, int n_in,
                              void* d_out, int out_size, void* d_ws, size_t ws_size,
                              hipStream_t stream) {
  const float* h_read = (const float*)d_in[0];
  const int* esrc = (const int*)d_in[1];
  const int* edst = (const int*)d_in[2];
  const float* W0 = (const float*)d_in[3];
  const float* b0 = (const float*)d_in[4];
  const float* W1 = (const float*)d_in[5];
  const float* b1 = (const float*)d_in[6];
  const float* W2 = (const float*)d_in[7];
  const float* b2 = (const float*)d_in[8];
  const float* W3 = (const float*)d_in[9];
  const float* b3 = (const float*)d_in[10];
  const float* W4 = (const float*)d_in[11];
  const float* b4 = (const float*)d_in[12];
  const float* W5 = (const float*)d_in[13];
  const float* b5 = (const float*)d_in[14];
  const float* atts = (const float*)d_in[15];
  const float* fcw = (const float*)d_in[16];
  const float* fcb = (const float*)d_in[17];
  float* out = (float*)d_out;

  char* w = (char*)d_ws;
  size_t off = 0;
  auto alloc = [&](size_t bytes) -> void* {
    void* p = w + off;
    off += (bytes + 15) & ~(size_t)15;  // 16B-align every array
    return p;
  };
  int* rp_r = (int*)alloc((N_READ + 1) * 4);
  int* rp_i = (int*)alloc((N_INTRON + 1) * 4);
  int* bsum = (int*)alloc(1024 * 4);
  float* rs_r = (float*)alloc(N_READ * 4);
  float* rs_i = (float*)alloc(N_INTRON * 4);
  unsigned short* csr_di_r = (unsigned short*)alloc(N_EDGES * 2);  // intron ids by read (~sorted)
  int* csr_si_i = (int*)alloc(N_EDGES * 4);                        // read ids by intron (~sorted)
  float* W0p = (float*)alloc(16 * 64 * 4);
  int* hist = (int*)alloc(NITEMS * 4);
  int* scanB = (int*)alloc((NITEMS + 1) * 4);   // read-bucket scan (lives to fineP2)
  int* scanAC = (int*)alloc((NITEMS + 1) * 4);  // intron-bucket scan (P1, reused for P3)
  float* hR = (float*)alloc((size_t)N_READ * 128 * 4);
  float* hI = (float*)alloc((size_t)N_INTRON * 128 * 4);
  // Time-multiplexed aliases inside hR (dead until L1 writes it):
  //   h16 lives prep_h0 -> L0 at hR+0 (12.8 MB);
  //   sort streams live at hR+16MB: A_read 8, A_intr 4, B2 8, C_read 8, C_intr 4, D 8 = 40 MB.
  float* h16 = hR;
  char* sbase = (char*)hR + (size_t)16 * 1024 * 1024;
  int* A_read = (int*)sbase;
  unsigned short* A_intr = (unsigned short*)(sbase + (size_t)8 * 1024 * 1024);
  unsigned* B2 = (unsigned*)(sbase + (size_t)12 * 1024 * 1024);
  int* C_read = (int*)(sbase + (size_t)20 * 1024 * 1024);
  unsigned short* C_intr = (unsigned short*)(sbase + (size_t)28 * 1024 * 1024);
  unsigned* D = (unsigned*)(sbase + (size_t)32 * 1024 * 1024);

  const int gS = NITEMS / 256;  // 782

  // --- P1: bucket edges by intron (stream becomes ~intron-sorted) ---
  kb_hist_i32<<<NB, 256, 0, stream>>>(edst, 6, hist);
  k_scan1<<<gS, 256, 0, stream>>>(hist, scanAC, bsum, NITEMS);
  k_scan2<<<1, 1024, 0, stream>>>(bsum, gS);
  k_scan3b<<<gS, 256, 0, stream>>>(scanAC, bsum, NITEMS);
  kb_scat1<<<NB, 256, 0, stream>>>(esrc, edst, scanAC, A_read, A_intr);

  // --- P2: counting-sort intron-ordered stream by read -> csr_di_r (introns sorted per read) ---
  kb_hist_i32<<<NB, 256, 0, stream>>>(A_read, 8, hist);
  k_scan1<<<gS, 256, 0, stream>>>(hist, scanB, bsum, NITEMS);
  k_scan2<<<1, 1024, 0, stream>>>(bsum, gS);
  k_scan3b<<<gS, 256, 0, stream>>>(scanB, bsum, NITEMS);
  kb_scat2<<<NB, 256, 0, stream>>>(A_read, A_intr, scanB, B2, C_read, C_intr);
  kb_fine<256, 8, unsigned short><<<NBUK, 256, 0, stream>>>(B2, scanB, rp_r, rs_r, csr_di_r, N_READ);

  // --- P3: counting-sort read-ordered stream by intron -> csr_si_i (reads sorted per intron) ---
  kb_hist_u16<<<NB, 256, 0, stream>>>(C_intr, 6, hist);
  k_scan1<<<gS, 256, 0, stream>>>(hist, scanAC, bsum, NITEMS);
  k_scan2<<<1, 1024, 0, stream>>>(bsum, gS);
  k_scan3b<<<gS, 256, 0, stream>>>(scanAC, bsum, NITEMS);
  kb_scat3<<<NB, 256, 0, stream>>>(C_read, C_intr, scanAC, D);
  kb_fine<64, 6, int><<<NBUK, 256, 0, stream>>>(D, scanAC, rp_i, rs_i, csr_si_i, N_INTRON);

  k_prep_h0<<<(N_READ * 16 + 255) / 256, 256, 0, stream>>>(h_read, rs_r, h16);
  k_prep_W0<<<4, 256, 0, stream>>>(W0, W0p);

  // --- 6 fused layers ---
  const int gI = (N_INTRON + 31) / 32;  // 1563
  const int gR = (N_READ + 31) / 32;    // 6250
  // L0: read->intron, 16(pad)->64 (int eidx)
  k_layer<16, 64, false, int><<<gI, 256, 0, stream>>>(
      h16, rp_i, csr_si_i, rs_i, W0p, b0, atts, 0, rs_i, hI, nullptr, nullptr, nullptr, N_INTRON);
  // L1: intron->read, 64->128 (u16 eidx)
  k_layer<64, 128, false, unsigned short><<<gR, 256, 0, stream>>>(
      hI, rp_r, csr_di_r, rs_r, W1, b1, atts, 1, rs_r, hR, nullptr, nullptr, nullptr, N_READ);
  // L2: read->intron, 128->128
  k_layer<128, 128, false, int><<<gI, 256, 0, stream>>>(
      hR, rp_i, csr_si_i, rs_i, W2, b2, atts, 2, rs_i, hI, nullptr, nullptr, nullptr, N_INTRON);
  // L3: intron->read
  k_layer<128, 128, false, unsigned short><<<gR, 256, 0, stream>>>(
      hI, rp_r, csr_di_r, rs_r, W3, b3, atts, 3, rs_r, hR, nullptr, nullptr, nullptr, N_READ);
  // L4: read->intron
  k_layer<128, 128, false, int><<<gI, 256, 0, stream>>>(
      hR, rp_i, csr_si_i, rs_i, W4, b4, atts, 4, rs_i, hI, nullptr, nullptr, nullptr, N_INTRON);
  // L5: intron->read, fc fused in-block (no hR store, no separate fc kernel)
  k_layer<128, 128, true, unsigned short><<<gR, 256, 0, stream>>>(
      hI, rp_r, csr_di_r, rs_r, W5, b5, atts, 5, nullptr, hR, fcw, fcb, out, N_READ);
}

// Round 6
// 868.456 us; speedup vs baseline: 1.4055x; 1.4055x over previous
//
#include <hip/hip_runtime.h>

#define N_READ   200000
#define N_INTRON 50000
#define N_EDGES  2000000

#define NB    256                          // edge-segment blocks for hist/scatter
#define EPB   ((N_EDGES + NB - 1) / NB)    // 7813 edges per block
#define NBUK  782                          // buckets per direction (782*64>=50000, 782*256>=200000)
#define SH_I  6                            // intron bucket shift: 64 introns/bucket
#define SH_R  8                            // read bucket shift: 256 reads/bucket
#define NITEMS (NBUK * NB)                 // 200192 (divisible by 256)

typedef float f4 __attribute__((ext_vector_type(4)));
typedef float f2 __attribute__((ext_vector_type(2)));
typedef int   i4 __attribute__((ext_vector_type(4)));
typedef unsigned u32x2 __attribute__((ext_vector_type(2)));
typedef unsigned short u16x4 __attribute__((ext_vector_type(4)));

// bf16 helpers: storage-only bf16; all math in f32.
static __device__ __forceinline__ unsigned short f2bf(float x) {
  unsigned u = __builtin_bit_cast(unsigned, x);
  u = (u + 0x7fffu + ((u >> 16) & 1u)) >> 16;  // RTNE
  return (unsigned short)u;
}
static __device__ __forceinline__ void gacc(f4& a, u32x2 u) {
  a[0] += __builtin_bit_cast(float, u.x << 16);
  a[1] += __builtin_bit_cast(float, u.x & 0xffff0000u);
  a[2] += __builtin_bit_cast(float, u.y << 16);
  a[3] += __builtin_bit_cast(float, u.y & 0xffff0000u);
}

// ---------------- bucket histograms (per-block LDS, no global atomics) ----------------
__global__ void kb_hist(const int* __restrict__ src, const int* __restrict__ dst,
                        int* __restrict__ histI, int* __restrict__ histR) {
  __shared__ int hI[1024], hR[1024];
  const int t = threadIdx.x, b = blockIdx.x;
  for (int k = t; k < 1024; k += 256) { hI[k] = 0; hR[k] = 0; }
  __syncthreads();
  const int s0 = b * EPB;
  const int s1 = (s0 + EPB < N_EDGES) ? s0 + EPB : N_EDGES;
  for (int i = s0 + t; i < s1; i += 256) {
    atomicAdd(&hI[dst[i] >> SH_I], 1);
    atomicAdd(&hR[src[i] >> SH_R], 1);
  }
  __syncthreads();
  for (int k = t; k < NBUK; k += 256) {
    histI[k * NB + b] = hI[k];
    histR[k * NB + b] = hR[k];
  }
}

// ---------------- exclusive scan (3 phases) ----------------
__global__ void k_scan1(const int* __restrict__ cnt, int* __restrict__ rp,
                        int* __restrict__ bsum, int n) {
  __shared__ int lds[256];
  int t = threadIdx.x;
  int i = blockIdx.x * 256 + t;
  int v = (i < n) ? cnt[i] : 0;
  lds[t] = v;
  __syncthreads();
  for (int off = 1; off < 256; off <<= 1) {
    int x = (t >= off) ? lds[t - off] : 0;
    __syncthreads();
    lds[t] += x;
    __syncthreads();
  }
  if (i < n) rp[i + 1] = lds[t];
  if (t == 255) bsum[blockIdx.x] = lds[255];
}

__global__ void k_scan2(int* __restrict__ bsum, int nb) {
  __shared__ int lds[1024];
  int t = threadIdx.x;
  int v = (t < nb) ? bsum[t] : 0;
  lds[t] = v;
  __syncthreads();
  for (int off = 1; off < 1024; off <<= 1) {
    int x = (t >= off) ? lds[t - off] : 0;
    __syncthreads();
    lds[t] += x;
    __syncthreads();
  }
  if (t < nb) bsum[t] = lds[t];
}

__global__ void k_scan3b(int* __restrict__ rp, const int* __restrict__ bsum, int n) {
  int i = blockIdx.x * 256 + threadIdx.x;
  if (i >= n) return;
  int off = (blockIdx.x == 0) ? 0 : bsum[blockIdx.x - 1];
  rp[i + 1] += off;
  if (i == 0) rp[0] = 0;
}

// ---------------- scatter edges into buckets (LDS cursors, packed u32 records) ----------------
__global__ void kb_scatter(const int* __restrict__ src, const int* __restrict__ dst,
                           const int* __restrict__ scanI, const int* __restrict__ scanR,
                           unsigned* __restrict__ bI, unsigned* __restrict__ bR) {
  __shared__ int cI[1024], cR[1024];
  const int t = threadIdx.x, b = blockIdx.x;
  for (int k = t; k < NBUK; k += 256) {
    cI[k] = scanI[k * NB + b];
    cR[k] = scanR[k * NB + b];
  }
  __syncthreads();
  const int s0 = b * EPB;
  const int s1 = (s0 + EPB < N_EDGES) ? s0 + EPB : N_EDGES;
  for (int i = s0 + t; i < s1; i += 256) {
    int s = src[i], d = dst[i];
    int slot = atomicAdd(&cI[d >> SH_I], 1);
    bI[slot] = ((unsigned)s << SH_I) | (unsigned)(d & 63);        // 18+6 = 24 bits
    int slot2 = atomicAdd(&cR[s >> SH_R], 1);
    bR[slot2] = ((unsigned)d << SH_R) | (unsigned)(s & 255);      // 16+8 = 24 bits
  }
}

// ---------------- fine CSR per bucket: local hist + LDS scan + scatter ----------------
template <int NBINS, int SH, typename PT>
__global__ void kb_fine(const unsigned* __restrict__ bk, const int* __restrict__ scan,
                        int* __restrict__ rp, float* __restrict__ rs,
                        PT* __restrict__ csr, int n_nodes) {
  __shared__ int hist[NBINS], cur[NBINS], lds[256];
  const int t = threadIdx.x, k = blockIdx.x;
  for (int j = t; j < NBINS; j += 256) hist[j] = 0;
  __syncthreads();
  const int s0 = scan[k * NB];
  const int e0 = (k + 1 < NBUK) ? scan[(k + 1) * NB] : N_EDGES;
  for (int i = s0 + t; i < e0; i += 256) atomicAdd(&hist[bk[i] & (NBINS - 1)], 1);
  __syncthreads();
  int v = (t < NBINS) ? hist[t] : 0;
  lds[t] = v;
  __syncthreads();
  for (int off = 1; off < 256; off <<= 1) {
    int x = (t >= off) ? lds[t - off] : 0;
    __syncthreads();
    lds[t] += x;
    __syncthreads();
  }
  if (t < NBINS) {
    int base = s0 + lds[t] - hist[t];
    cur[t] = base;
    int n = k * NBINS + t;
    if (n < n_nodes) {
      rp[n] = base;
      rs[n] = rsqrtf((float)(hist[t] > 0 ? hist[t] : 1));
    }
  }
  if (k == NBUK - 1 && t == 0) rp[n_nodes] = N_EDGES;
  __syncthreads();
  for (int i = s0 + t; i < e0; i += 256) {
    unsigned v2 = bk[i];
    int slot = atomicAdd(&cur[v2 & (NBINS - 1)], 1);
    csr[slot] = (PT)(v2 >> SH);
  }
}

// ---------------- layer-0 input prep: pad 10->16 and pre-scale by rs_read ----------------
__global__ void k_prep_h0(const float* __restrict__ h_read, const float* __restrict__ rs_r,
                          float* __restrict__ h16) {
  int i = blockIdx.x * blockDim.x + threadIdx.x;
  if (i >= N_READ * 16) return;
  int n = i >> 4, c = i & 15;
  h16[i] = (c < 10) ? h_read[n * 10 + c] * rs_r[n] : 0.0f;
}

__global__ void k_prep_W0(const float* __restrict__ W0, float* __restrict__ W0p) {
  int i = blockIdx.x * blockDim.x + threadIdx.x;
  if (i >= 16 * 64) return;
  int k = i >> 6, j = i & 63;
  W0p[i] = (k < 10) ? W0[k * 64 + j] : 0.0f;
}

// ---------------- fused aggregate + GEMM + epilogue layer ----------------
// BF16SRC: gather source stored bf16 (convert to f32 before accumulate).
// BF16DST: epilogue stores bf16 (RTNE). All arithmetic/LDS f32.
// FC=true (L5): keep output tile in LDS, apply 128->2 projection in-block.
template <int DIN, int DOUT, bool FC, bool BF16SRC, bool BF16DST, typename ET>
__launch_bounds__(256)
__global__ void k_layer(const void* __restrict__ hsrc_, const int* __restrict__ rp,
                        const ET* __restrict__ eidx, const float* __restrict__ rs_dst,
                        const float* __restrict__ W, const float* __restrict__ bias,
                        const float* __restrict__ atts, int li,
                        const float* __restrict__ rs_next,  // may be null
                        void* __restrict__ hout_,
                        const float* __restrict__ fcw, const float* __restrict__ fcb,
                        float* __restrict__ fcout, int n_dst) {
  constexpr int NT = 32;
  constexpr int RSTR = DIN + 4;  // padded LDS row stride (floats)
  __shared__ float rows[NT * RSTR];
  const int tid = threadIdx.x;
  const int nbase = blockIdx.x * NT;
  const int team = tid >> 6, lane = tid & 63;
  const float* hs_f = (const float*)hsrc_;
  const unsigned short* hs_b = (const unsigned short*)hsrc_;

  if constexpr (DIN >= 64) {
    constexpr int LPN = DIN / 4;   // lanes per node: 32 (DIN=128) or 16 (DIN=64)
    constexpr int NPW = 64 / LPN;  // nodes per wave pass: 2 or 4
    const int sub = lane / LPN, lc = lane % LPN;
    for (int tl = 0; tl < 8 / NPW; ++tl) {
      const int t = team * 8 + tl * NPW + sub;
      const int n = nbase + t;
      f4 a0 = {0.f, 0.f, 0.f, 0.f}, a1 = a0, a2 = a0, a3 = a0;
      if (n < n_dst) {
        const int e0 = rp[n], e1 = rp[n + 1];
        int e = e0;
        for (; e + 4 <= e1; e += 4) {
          int s0 = (int)eidx[e], s1 = (int)eidx[e + 1];
          int s2 = (int)eidx[e + 2], s3 = (int)eidx[e + 3];
          if constexpr (BF16SRC) {
            gacc(a0, *(const u32x2*)&hs_b[(size_t)s0 * DIN + lc * 4]);
            gacc(a1, *(const u32x2*)&hs_b[(size_t)s1 * DIN + lc * 4]);
            gacc(a2, *(const u32x2*)&hs_b[(size_t)s2 * DIN + lc * 4]);
            gacc(a3, *(const u32x2*)&hs_b[(size_t)s3 * DIN + lc * 4]);
          } else {
            a0 += *(const f4*)&hs_f[(size_t)s0 * DIN + lc * 4];
            a1 += *(const f4*)&hs_f[(size_t)s1 * DIN + lc * 4];
            a2 += *(const f4*)&hs_f[(size_t)s2 * DIN + lc * 4];
            a3 += *(const f4*)&hs_f[(size_t)s3 * DIN + lc * 4];
          }
        }
        for (; e < e1; ++e) {
          int s0 = (int)eidx[e];
          if constexpr (BF16SRC) gacc(a0, *(const u32x2*)&hs_b[(size_t)s0 * DIN + lc * 4]);
          else a0 += *(const f4*)&hs_f[(size_t)s0 * DIN + lc * 4];
        }
        a0 = (a0 + a1) + (a2 + a3);
        a0 *= rs_dst[n];
      }
      *(f4*)&rows[t * RSTR + lc * 4] = a0;
    }
  } else {  // DIN == 16, f32 source (L0)
    const int sub = lane >> 3, l8 = lane & 7;
    const int t = team * 8 + sub;
    const int n = nbase + t;
    f2 a0 = {0.f, 0.f}, a1 = a0, a2 = a0, a3 = a0;
    if (n < n_dst) {
      const int e0 = rp[n], e1 = rp[n + 1];
      int e = e0;
      for (; e + 4 <= e1; e += 4) {
        int s0 = (int)eidx[e], s1 = (int)eidx[e + 1];
        int s2 = (int)eidx[e + 2], s3 = (int)eidx[e + 3];
        a0 += *(const f2*)&hs_f[(size_t)s0 * 16 + l8 * 2];
        a1 += *(const f2*)&hs_f[(size_t)s1 * 16 + l8 * 2];
        a2 += *(const f2*)&hs_f[(size_t)s2 * 16 + l8 * 2];
        a3 += *(const f2*)&hs_f[(size_t)s3 * 16 + l8 * 2];
      }
      for (; e < e1; ++e) a0 += *(const f2*)&hs_f[(size_t)(int)eidx[e] * 16 + l8 * 2];
      a0 = (a0 + a1) + (a2 + a3);
      a0 *= rs_dst[n];
    }
    *(f2*)&rows[t * RSTR + l8 * 2] = a0;
  }
  __syncthreads();

  // GEMM: thread computes NPT nodes x 4 cols; nodes interleaved by NG
  constexpr int JG = DOUT / 4;
  constexpr int NG = 256 / JG;
  constexpr int NPT = NT / NG;
  const int jg = tid % JG, ng = tid / JG;
  const int j0 = jg * 4;

  f4 acc[NPT];
#pragma unroll
  for (int p = 0; p < NPT; ++p) acc[p] = (f4){0.f, 0.f, 0.f, 0.f};

#pragma unroll 2
  for (int k = 0; k < DIN; k += 4) {
    f4 w[4];
#pragma unroll
    for (int u = 0; u < 4; ++u) w[u] = *(const f4*)&W[(k + u) * DOUT + j0];
#pragma unroll
    for (int p = 0; p < NPT; ++p) {
      f4 r = *(const f4*)&rows[(ng + p * NG) * RSTR + k];
#pragma unroll
      for (int u = 0; u < 4; ++u) acc[p] += r[u] * w[u];
    }
  }

  const float gate = 1.f / (1.f + __expf(-atts[li]));
  const f4 b4 = *(const f4*)&bias[j0];

  if constexpr (!FC) {
#pragma unroll
    for (int p = 0; p < NPT; ++p) {
      const int nl = ng + p * NG;
      const int n = nbase + nl;
      if (n < n_dst) {
        f4 v = (acc[p] + b4) * gate;
#pragma unroll
        for (int c = 0; c < 4; ++c) v[c] = fmaxf(v[c], 0.f);
        if (rs_next) v *= rs_next[n];
        if constexpr (BF16DST) {
          u16x4 o = {f2bf(v[0]), f2bf(v[1]), f2bf(v[2]), f2bf(v[3])};
          *(u16x4*)&((unsigned short*)hout_)[(size_t)n * DOUT + j0] = o;
        } else {
          *(f4*)&((float*)hout_)[(size_t)n * DOUT + j0] = v;
        }
      }
    }
  } else {
    __syncthreads();  // everyone done reading rows before we overwrite it
#pragma unroll
    for (int p = 0; p < NPT; ++p) {
      const int nl = ng + p * NG;
      f4 v = (acc[p] + b4) * gate;
#pragma unroll
      for (int c = 0; c < 4; ++c) v[c] = fmaxf(v[c], 0.f);
      *(f4*)&rows[nl * RSTR + j0] = v;
    }
    __syncthreads();
    // fc: 256 threads = 32 nodes x 2 cols x 4 partial-sums
    const int nl = tid >> 3, c = (tid >> 2) & 1, part = tid & 3;
    float s = 0.f;
    const int k0 = part * 32;
#pragma unroll 8
    for (int k = k0; k < k0 + 32; ++k) s += rows[nl * RSTR + k] * fcw[k * 2 + c];
    s += __shfl_xor(s, 1);
    s += __shfl_xor(s, 2);
    const int n = nbase + nl;
    if (part == 0 && n < n_dst) fcout[n * 2 + c] = s + fcb[c];
  }
}

extern "C" void kernel_launch(void* const* d_in, const int* in_sizes, int n_in,
                              void* d_out, int out_size, void* d_ws, size_t ws_size,
                              hipStream_t stream) {
  const float* h_read = (const float*)d_in[0];
  const int* esrc = (const int*)d_in[1];
  const int* edst = (const int*)d_in[2];
  const float* W0 = (const float*)d_in[3];
  const float* b0 = (const float*)d_in[4];
  const float* W1 = (const float*)d_in[5];
  const float* b1 = (const float*)d_in[6];
  const float* W2 = (const float*)d_in[7];
  const float* b2 = (const float*)d_in[8];
  const float* W3 = (const float*)d_in[9];
  const float* b3 = (const float*)d_in[10];
  const float* W4 = (const float*)d_in[11];
  const float* b4 = (const float*)d_in[12];
  const float* W5 = (const float*)d_in[13];
  const float* b5 = (const float*)d_in[14];
  const float* atts = (const float*)d_in[15];
  const float* fcw = (const float*)d_in[16];
  const float* fcb = (const float*)d_in[17];
  float* out = (float*)d_out;

  char* w = (char*)d_ws;
  size_t off = 0;
  auto alloc = [&](size_t bytes) -> void* {
    void* p = w + off;
    off += (bytes + 15) & ~(size_t)15;  // 16B-align every array
    return p;
  };
  int* rp_r = (int*)alloc((N_READ + 1) * 4);
  int* rp_i = (int*)alloc((N_INTRON + 1) * 4);
  int* bsum = (int*)alloc(1024 * 4);
  float* rs_r = (float*)alloc(N_READ * 4);
  float* rs_i = (float*)alloc(N_INTRON * 4);
  unsigned short* csr_di_r = (unsigned short*)alloc(N_EDGES * 2);  // intron ids by read
  int* csr_si_i = (int*)alloc(N_EDGES * 4);                        // read ids by intron
  float* W0p = (float*)alloc(16 * 64 * 4);
  int* histI = (int*)alloc(NITEMS * 4);
  int* scanI = (int*)alloc((NITEMS + 1) * 4);
  int* histR = (int*)alloc(NITEMS * 4);
  int* scanR = (int*)alloc((NITEMS + 1) * 4);
  unsigned short* hR = (unsigned short*)alloc((size_t)N_READ * 128 * 2);    // bf16 features
  unsigned short* hI = (unsigned short*)alloc((size_t)N_INTRON * 128 * 2);  // bf16 features
  // Time-multiplexed aliases inside hR's 51.2 MB (dead until L1 writes it):
  //   h16 (f32, 12.8 MB) lives prep_h0 -> L0 at hR+0;
  //   bucketed edge records live kb_scatter -> kb_fine at hR+16MB (2x8 MB).
  float* h16 = (float*)hR;
  unsigned* bI = (unsigned*)((char*)hR + (size_t)16 * 1024 * 1024);
  unsigned* bR = bI + N_EDGES;

  // --- CSR build: bucket histogram -> scan -> scatter -> per-bucket fine CSR ---
  kb_hist<<<NB, 256, 0, stream>>>(esrc, edst, histI, histR);
  k_scan1<<<NITEMS / 256, 256, 0, stream>>>(histI, scanI, bsum, NITEMS);
  k_scan2<<<1, 1024, 0, stream>>>(bsum, NITEMS / 256);
  k_scan3b<<<NITEMS / 256, 256, 0, stream>>>(scanI, bsum, NITEMS);
  k_scan1<<<NITEMS / 256, 256, 0, stream>>>(histR, scanR, bsum, NITEMS);
  k_scan2<<<1, 1024, 0, stream>>>(bsum, NITEMS / 256);
  k_scan3b<<<NITEMS / 256, 256, 0, stream>>>(scanR, bsum, NITEMS);
  kb_scatter<<<NB, 256, 0, stream>>>(esrc, edst, scanI, scanR, bI, bR);
  kb_fine<64, SH_I, int><<<NBUK, 256, 0, stream>>>(bI, scanI, rp_i, rs_i, csr_si_i, N_INTRON);
  kb_fine<256, SH_R, unsigned short><<<NBUK, 256, 0, stream>>>(bR, scanR, rp_r, rs_r, csr_di_r, N_READ);

  k_prep_h0<<<(N_READ * 16 + 255) / 256, 256, 0, stream>>>(h_read, rs_r, h16);
  k_prep_W0<<<4, 256, 0, stream>>>(W0, W0p);

  // --- 6 fused layers (features stored bf16, math f32) ---
  const int gI = (N_INTRON + 31) / 32;  // 1563
  const int gR = (N_READ + 31) / 32;    // 6250
  // L0: read->intron, 16(pad)->64, src f32 h16, dst bf16 hI
  k_layer<16, 64, false, false, true, int><<<gI, 256, 0, stream>>>(
      h16, rp_i, csr_si_i, rs_i, W0p, b0, atts, 0, rs_i, hI, nullptr, nullptr, nullptr, N_INTRON);
  // L1: intron->read, 64->128, src bf16 hI, dst bf16 hR
  k_layer<64, 128, false, true, true, unsigned short><<<gR, 256, 0, stream>>>(
      hI, rp_r, csr_di_r, rs_r, W1, b1, atts, 1, rs_r, hR, nullptr, nullptr, nullptr, N_READ);
  // L2: read->intron, 128->128, src bf16 hR, dst bf16 hI
  k_layer<128, 128, false, true, true, int><<<gI, 256, 0, stream>>>(
      hR, rp_i, csr_si_i, rs_i, W2, b2, atts, 2, rs_i, hI, nullptr, nullptr, nullptr, N_INTRON);
  // L3: intron->read, src bf16 hI, dst bf16 hR
  k_layer<128, 128, false, true, true, unsigned short><<<gR, 256, 0, stream>>>(
      hI, rp_r, csr_di_r, rs_r, W3, b3, atts, 3, rs_r, hR, nullptr, nullptr, nullptr, N_READ);
  // L4: read->intron, src bf16 hR, dst bf16 hI
  k_layer<128, 128, false, true, true, int><<<gI, 256, 0, stream>>>(
      hR, rp_i, csr_si_i, rs_i, W4, b4, atts, 4, rs_i, hI, nullptr, nullptr, nullptr, N_INTRON);
  // L5: intron->read, src bf16 hI, fc fused in-block (f32 out)
  k_layer<128, 128, true, true, false, unsigned short><<<gR, 256, 0, stream>>>(
      hI, rp_r, csr_di_r, rs_r, W5, b5, atts, 5, nullptr, nullptr, fcw, fcb, out, N_READ);
}